// Round 7
// baseline (123.876 us; speedup 1.0000x reference)
//
#include <hip/hip_runtime.h>
#include <stdint.h>

#define VSZ 30000
#define TPS 2048      // trees per side
#define G3  384

// workspace layout (float offsets)
#define OFF_PROJ   0u          // 30000*128 bf16 = 1,920,000 floats
#define OFF_WCT    1920000u    // 128*128
#define OFF_SEQ    1936384u    // 2*2048*128
#define OFF_HFIN   2460672u    // 256*128

using f32x4 = __attribute__((ext_vector_type(4))) float;
using s16x8 = __attribute__((ext_vector_type(8))) short;
union U8 { uint4 u; s16x8 s; };

__device__ __forceinline__ float sigm(float x) { return 1.0f / (1.0f + __expf(-x)); }
__device__ __forceinline__ float tanh_fast(float x) {
  float e = __expf(-2.0f * x);
  return 2.0f / (1.0f + e) - 1.0f;   // safe at both tails (no inf/inf)
}
__device__ __forceinline__ unsigned bf16_rn(float f) {
  unsigned u = __float_as_uint(f);
  return (u + 0x7FFFu + ((u >> 16) & 1u)) >> 16;   // round-to-nearest-even
}

// ---- K0: transpose src[R][128] -> dst[128][R]   (R % 32 == 0)
__global__ __launch_bounds__(256) void k_transpose(const float* __restrict__ src,
                                                   float* __restrict__ dst, int R) {
  __shared__ float tile[32][129];
  int r0 = blockIdx.x * 32;
  for (int idx = threadIdx.x; idx < 32 * 128; idx += 256) {
    int r = idx >> 7, c = idx & 127;
    tile[r][c] = src[(r0 + r) * 128 + c];
  }
  __syncthreads();
  for (int idx = threadIdx.x; idx < 32 * 128; idx += 256) {
    int k = idx >> 5, r = idx & 31;
    dst[k * R + r0 + r] = tile[r][k];
  }
}

// ---- K1: proj[v][eo] = b_c[eo] + sum_k emb[v][k] * w_c[eo][k]; output bf16
__global__ __launch_bounds__(256) void k_proj(const float* __restrict__ emb,
                                              const float* __restrict__ wcT,
                                              const float* __restrict__ b_c,
                                              unsigned short* __restrict__ projb) {
  __shared__ float wT[128 * 128];     // 64 KB, [k][eo]
  __shared__ float es[32][128];       // 16 KB
  int v0 = blockIdx.x * 32;
  for (int idx = threadIdx.x; idx < 128 * 32; idx += 256)
    ((float4*)wT)[idx] = ((const float4*)wcT)[idx];
  for (int idx = threadIdx.x; idx < 32 * 32; idx += 256) {
    int v = idx >> 5;
    float4 val = make_float4(0.f, 0.f, 0.f, 0.f);
    if (v0 + v < VSZ) val = ((const float4*)emb)[v0 * 32 + idx];
    ((float4*)es)[idx] = val;
  }
  __syncthreads();
  int tv = (threadIdx.x >> 5) << 2;   // v base (0..28)
  int te = (threadIdx.x & 31) << 2;   // eo base (0..124)
  float4 bc4 = *(const float4*)&b_c[te];
  float4 a0 = bc4, a1 = bc4, a2 = bc4, a3 = bc4;
#pragma unroll 4
  for (int kk = 0; kk < 128; ++kk) {
    float4 w4 = *(float4*)&wT[kk * 128 + te];
    float e0 = es[tv + 0][kk], e1 = es[tv + 1][kk];
    float e2 = es[tv + 2][kk], e3 = es[tv + 3][kk];
    a0.x = fmaf(e0, w4.x, a0.x); a0.y = fmaf(e0, w4.y, a0.y);
    a0.z = fmaf(e0, w4.z, a0.z); a0.w = fmaf(e0, w4.w, a0.w);
    a1.x = fmaf(e1, w4.x, a1.x); a1.y = fmaf(e1, w4.y, a1.y);
    a1.z = fmaf(e1, w4.z, a1.z); a1.w = fmaf(e1, w4.w, a1.w);
    a2.x = fmaf(e2, w4.x, a2.x); a2.y = fmaf(e2, w4.y, a2.y);
    a2.z = fmaf(e2, w4.z, a2.z); a2.w = fmaf(e2, w4.w, a2.w);
    a3.x = fmaf(e3, w4.x, a3.x); a3.y = fmaf(e3, w4.y, a3.y);
    a3.z = fmaf(e3, w4.z, a3.z); a3.w = fmaf(e3, w4.w, a3.w);
  }
#pragma unroll
  for (int i = 0; i < 4; ++i) {
    float4 a = (i == 0) ? a0 : (i == 1) ? a1 : (i == 2) ? a2 : a3;
    int v = v0 + tv + i;
    if (v < VSZ) {
      uint2 u;
      u.x = bf16_rn(a.x) | (bf16_rn(a.y) << 16);
      u.y = bf16_rn(a.z) | (bf16_rn(a.w) << 16);
      *(uint2*)&projb[(size_t)v * 128 + te] = u;
    }
  }
}

// ---- K2: per-tree subtree sums (heap), coord-wise max, ReLU -> seq[side][t][c]
__global__ __launch_bounds__(256) void k_tree(const int* __restrict__ tokens1,
                                              const int* __restrict__ tokens2,
                                              const unsigned short* __restrict__ projb,
                                              float* __restrict__ seq) {
  __shared__ int tok[2][64];
  int side = blockIdx.y;
  const int* tokens = side ? tokens2 : tokens1;
  int t0 = blockIdx.x * 2;
  if (threadIdx.x < 128) {
    int tl = threadIdx.x >> 6, j = threadIdx.x & 63;
    tok[tl][j] = tokens[(t0 + tl) * 64 + j];
  }
  __syncthreads();
  int tl = threadIdx.x >> 7;
  int c  = threadIdx.x & 127;
  float s[64];
#pragma unroll
  for (int j = 0; j < 64; ++j)
    s[j] = __uint_as_float(((unsigned)projb[(size_t)tok[tl][j] * 128 + c]) << 16);
  // bottom-up subtree sums: children of j are 2j+1, 2j+2 (node 31 has only 63)
  s[31] += s[63];
#pragma unroll
  for (int j = 30; j >= 0; --j) s[j] += s[2 * j + 1] + s[2 * j + 2];
  float m = s[0];
#pragma unroll
  for (int j = 1; j < 64; ++j) m = fmaxf(m, s[j]);
  m = fmaxf(m, 0.0f);
  seq[(size_t)(side * TPS + t0 + tl) * 128 + c] = m;
}

// ---- K3: fused GRU scans via MFMA, gi computed on the fly.
//      grid = 16 blocks: blockIdx.x = (pg<<2)|sd, 512 threads = 8 waves.
//      x slice (16 programs x 32 steps x 128) staged bf16 in LDS; W_ih AND
//      W_hh held as persistent A-fragments in registers (96 VGPR).
//      amdgpu_waves_per_eu(2,2): occupancy pinned at what LDS allows anyway
//      -> allocator gets the 256-VGPR budget and stops rematerializing the
//      fragments (round 5/6: VGPR=92, loop re-built all 24 fragments from
//      global every step = ~1000 VALU inst/step = the 4200-cyc/step flatline).
//      asm "+v" keep-alives make the fragments non-rematerializable.
#define KT 1040     // bytes per ktile (64 lanes * 16B + 16B pad)
#define XS 4160     // bytes per step tile (4 ktiles)
#define MM(dst, A, B) dst = __builtin_amdgcn_mfma_f32_16x16x32_bf16(A, B, dst, 0, 0, 0)

__global__ __launch_bounds__(512)
__attribute__((amdgpu_waves_per_eu(2, 2)))
void k_scan(
    const float* __restrict__ seq,
    const float* __restrict__ w_ih_f, const float* __restrict__ w_ih_b,
    const float* __restrict__ w_hh_f, const float* __restrict__ w_hh_b,
    const float* __restrict__ b_ih_f, const float* __restrict__ b_ih_b,
    const float* __restrict__ b_hh_f, const float* __restrict__ b_hh_b,
    float* __restrict__ hfin) {
  __shared__ __align__(16) unsigned lds[35360];   // 141440 B: 32 x-tiles + 2 h-tiles
  int bx = blockIdx.x;
  int sd = bx & 3, pg = bx >> 2;
  int side = sd >> 1, dir = sd & 1;
  const float* wih = dir ? w_ih_b : w_ih_f;
  const float* whh = dir ? w_hh_b : w_hh_f;
  const float* bih = dir ? b_ih_b : b_ih_f;
  const float* bhh = dir ? b_hh_b : b_hh_f;
  int tid = threadIdx.x;
  int w = tid >> 6, l = tid & 63;
  int p  = l & 15;          // program (B n / D col)
  int kb = l >> 4;          // k-block within fragment
  int c0 = 16 * w + 4 * kb; // D-row base: output rows c0..c0+3 for this lane

  // --- stage x -> LDS bf16 B-frag tiles (by sequence position)
  {
    int pp = tid >> 5, cc = tid & 31;
    int wbyte = (cc >> 3) * KT + (pp + 16 * ((cc & 7) >> 1)) * 16 + (cc & 1) * 8;
    const float* srow = seq + (size_t)(side * TPS + (pg * 16 + pp) * 32) * 128 + 4 * cc;
    for (int ss = 0; ss < 32; ++ss) {
      float4 v = *(const float4*)(srow + (size_t)ss * 128);
      uint2 u;
      u.x = bf16_rn(v.x) | (bf16_rn(v.y) << 16);
      u.y = bf16_rn(v.z) | (bf16_rn(v.w) << 16);
      *(uint2*)((char*)lds + ss * XS + wbyte) = u;
    }
  }
  // zero both h buffers (2 * 4160 B)
  for (int i = tid; i < 2080; i += 512) lds[32 * 1040 + i] = 0u;

  // --- persistent A-fragments (lane: rows 16w+p of each gate, k = t*32+kb*8+j)
  s16x8 ai[3][4], ah[3][4];
#pragma unroll
  for (int g = 0; g < 3; ++g)
#pragma unroll
    for (int t = 0; t < 4; ++t) {
      int row = g * 128 + 16 * w + p;
      int ks  = t * 32 + kb * 8;
      float4 f0 = *(const float4*)&wih[row * 128 + ks];
      float4 f1 = *(const float4*)&wih[row * 128 + ks + 4];
      U8 u;
      u.u.x = bf16_rn(f0.x) | (bf16_rn(f0.y) << 16);
      u.u.y = bf16_rn(f0.z) | (bf16_rn(f0.w) << 16);
      u.u.z = bf16_rn(f1.x) | (bf16_rn(f1.y) << 16);
      u.u.w = bf16_rn(f1.z) | (bf16_rn(f1.w) << 16);
      ai[g][t] = u.s;
      f0 = *(const float4*)&whh[row * 128 + ks];
      f1 = *(const float4*)&whh[row * 128 + ks + 4];
      u.u.x = bf16_rn(f0.x) | (bf16_rn(f0.y) << 16);
      u.u.y = bf16_rn(f0.z) | (bf16_rn(f0.w) << 16);
      u.u.z = bf16_rn(f1.x) | (bf16_rn(f1.y) << 16);
      u.u.w = bf16_rn(f1.z) | (bf16_rn(f1.w) << 16);
      ah[g][t] = u.s;
    }
  // pin fragments: opaque to rematerialization
#pragma unroll
  for (int g = 0; g < 3; ++g)
#pragma unroll
    for (int t = 0; t < 4; ++t) {
      asm volatile("" : "+v"(ai[g][t]));
      asm volatile("" : "+v"(ah[g][t]));
    }

  f32x4 bir = *(const f32x4*)&bih[c0],       bhr = *(const f32x4*)&bhh[c0];
  f32x4 biz = *(const f32x4*)&bih[128 + c0], bhz = *(const f32x4*)&bhh[128 + c0];
  f32x4 bin = *(const f32x4*)&bih[256 + c0], bhn = *(const f32x4*)&bhh[256 + c0];
  f32x4 bbr = bir + bhr, bbz = biz + bhz;

  // h write position in B-frag layout (k = c0.., n = p)
  int hwb = (c0 >> 5) * KT + (p + 16 * ((c0 & 31) >> 3)) * 16 + (c0 & 7) * 2;

  float hc[4] = {0.f, 0.f, 0.f, 0.f};
  f32x4 z4 = {0.f, 0.f, 0.f, 0.f};
  __syncthreads();

  for (int i = 0; i < 32; ++i) {
    int pos = dir ? (31 - i) : i;
    const char* xb = (const char*)lds + pos * XS;
    const char* hb = (const char*)lds + (32 + (i & 1)) * XS;
    s16x8 xf[4], bf[4];
#pragma unroll
    for (int t = 0; t < 4; ++t) {
      U8 ux; ux.u = *(const uint4*)(xb + t * KT + l * 16); xf[t] = ux.s;
      U8 uh; uh.u = *(const uint4*)(hb + t * KT + l * 16); bf[t] = uh.s;
    }
    f32x4 aR0 = z4, aR1 = z4, aZ0 = z4, aZ1 = z4;
    f32x4 aNi0 = z4, aNi1 = z4, aNh0 = z4, aNh1 = z4;
    MM(aR0,  ai[0][0], xf[0]); MM(aR1,  ai[0][1], xf[1]);
    MM(aZ0,  ai[1][0], xf[0]); MM(aZ1,  ai[1][1], xf[1]);
    MM(aNi0, ai[2][0], xf[0]); MM(aNi1, ai[2][1], xf[1]);
    MM(aNh0, ah[2][0], bf[0]); MM(aNh1, ah[2][1], bf[1]);
    MM(aR0,  ah[0][0], bf[0]); MM(aR1,  ah[0][1], bf[1]);
    MM(aZ0,  ah[1][0], bf[0]); MM(aZ1,  ah[1][1], bf[1]);
    MM(aNi0, ai[2][2], xf[2]); MM(aNi1, ai[2][3], xf[3]);
    MM(aNh0, ah[2][2], bf[2]); MM(aNh1, ah[2][3], bf[3]);
    MM(aR0,  ai[0][2], xf[2]); MM(aR1,  ai[0][3], xf[3]);
    MM(aZ0,  ai[1][2], xf[2]); MM(aZ1,  ai[1][3], xf[3]);
    MM(aR0,  ah[0][2], bf[2]); MM(aR1,  ah[0][3], bf[3]);
    MM(aZ0,  ah[1][2], bf[2]); MM(aZ1,  ah[1][3], bf[3]);
#pragma unroll
    for (int r4 = 0; r4 < 4; ++r4) {
      float rv = sigm(aR0[r4] + aR1[r4] + bbr[r4]);
      float zv = sigm(aZ0[r4] + aZ1[r4] + bbz[r4]);
      float nv = tanh_fast(aNi0[r4] + aNi1[r4] + bin[r4]
                           + rv * (aNh0[r4] + aNh1[r4] + bhn[r4]));
      hc[r4] = (1.0f - zv) * nv + zv * hc[r4];
    }
    uint2 hp;
    hp.x = bf16_rn(hc[0]) | (bf16_rn(hc[1]) << 16);
    hp.y = bf16_rn(hc[2]) | (bf16_rn(hc[3]) << 16);
    *(uint2*)((char*)lds + (32 + ((i + 1) & 1)) * XS + hwb) = hp;
    __syncthreads();
  }
  int scan = sd * 64 + pg * 16 + p;
#pragma unroll
  for (int r4 = 0; r4 < 4; ++r4)
    hfin[(size_t)scan * 128 + c0 + r4] = hc[r4];
}

// ---- K5: out[b] = sigmoid(|lvec-rvec| . w_out + b_out)
__global__ __launch_bounds__(64) void k_out(const float* __restrict__ hfin,
                                            const float* __restrict__ w_out,
                                            const float* __restrict__ b_out,
                                            float* __restrict__ out) {
  int b = blockIdx.x, lane = threadIdx.x;
  float p = 0.f;
#pragma unroll
  for (int i = 0; i < 2; ++i) {
    int c = lane + i * 64;
    float l = hfin[(size_t)(0   + b) * 128 + c] + hfin[(size_t)(64  + b) * 128 + c];
    float r = hfin[(size_t)(128 + b) * 128 + c] + hfin[(size_t)(192 + b) * 128 + c];
    p += fabsf(l - r) * w_out[c];
  }
#pragma unroll
  for (int off = 32; off > 0; off >>= 1) p += __shfl_down(p, off);
  if (lane == 0) out[b] = sigm(p + b_out[0]);
}

extern "C" void kernel_launch(void* const* d_in, const int* in_sizes, int n_in,
                              void* d_out, int out_size, void* d_ws, size_t ws_size,
                              hipStream_t stream) {
  (void)in_sizes; (void)n_in; (void)out_size; (void)ws_size;
  const int*   tokens1 = (const int*)d_in[0];
  const int*   tokens2 = (const int*)d_in[2];
  const float* emb     = (const float*)d_in[4];
  const float* w_c     = (const float*)d_in[5];
  const float* b_c     = (const float*)d_in[6];
  const float* w_ih_f  = (const float*)d_in[7];
  const float* w_hh_f  = (const float*)d_in[8];
  const float* b_ih_f  = (const float*)d_in[9];
  const float* b_hh_f  = (const float*)d_in[10];
  const float* w_ih_b  = (const float*)d_in[11];
  const float* w_hh_b  = (const float*)d_in[12];
  const float* b_ih_b  = (const float*)d_in[13];
  const float* b_hh_b  = (const float*)d_in[14];
  const float* w_out   = (const float*)d_in[15];
  const float* b_out   = (const float*)d_in[16];
  float* ws = (float*)d_ws;
  unsigned short* projb = (unsigned short*)(ws + OFF_PROJ);
  float* wcT    = ws + OFF_WCT;
  float* seq    = ws + OFF_SEQ;
  float* hfin   = ws + OFF_HFIN;

  k_transpose<<<4, 256, 0, stream>>>(w_c, wcT, 128);
  k_proj<<<(VSZ + 31) / 32, 256, 0, stream>>>(emb, wcT, b_c, projb);
  k_tree<<<dim3(TPS / 2, 2), 256, 0, stream>>>(tokens1, tokens2, projb, seq);
  k_scan<<<16, 512, 0, stream>>>(seq, w_ih_f, w_ih_b, w_hh_f, w_hh_b,
                                 b_ih_f, b_ih_b, b_hh_f, b_hh_b, hfin);
  k_out<<<64, 64, 0, stream>>>(hfin, w_out, b_out, (float*)d_out);
}